// Round 9
// baseline (353.904 us; speedup 1.0000x reference)
//
#include <hip/hip_runtime.h>

typedef unsigned short u16;
typedef unsigned int u32;
typedef __bf16 v8bf __attribute__((ext_vector_type(8)));
typedef float v4f __attribute__((ext_vector_type(4)));
typedef float v16f __attribute__((ext_vector_type(16)));

#define DEV __device__ __forceinline__

constexpr int CB = 4;     // batch
constexpr int C = 256;    // channels
constexpr int NN = 4096;  // voxels
constexpr float LOG2E = 1.4426950408889634f;
constexpr float MBOUND = 40.0f;  // static softmax shift (log2 units), R7-proven

constexpr int KP = 264;  // ksh row stride (u16): 132 words -> +4 bank phase/row
constexpr int VP = 36;   // vsh row stride (u16): 18 words -> 16 bases, ~2-way (free)
constexpr int PP = 36;   // psh row stride

DEV u16 f2bf(float f) {
  union { float f; u32 u; } v; v.f = f;
  u32 r = v.u + 0x7fffu + ((v.u >> 16) & 1u);  // RNE
  return (u16)(r >> 16);
}
DEV float bf2f(u16 h) {
  union { u32 u; float f; } v; v.u = ((u32)h) << 16; return v.f;
}

// ---------- fused x-transpose+cvt + q/k/v projection ----------
// x: (B,C,N) fp32; weights fp32 (C,C). qO,kO: (B,N,C) bf16 (q scaled C^-0.5*log2e);
// vO: (B,C,N) bf16. Grid (64, 2, CB): stage x-tile once, 6 phases (3 wsel x 2 ot).
__global__ __launch_bounds__(256) void k_qkv(
    const float* __restrict__ x, const float* __restrict__ wq,
    const float* __restrict__ wk, const float* __restrict__ wv,
    const float* __restrict__ bq, const float* __restrict__ bk,
    const float* __restrict__ bv, u16* __restrict__ qO, u16* __restrict__ kO,
    u16* __restrict__ vO) {
  __shared__ __align__(16) u16 Ash[64 * 264];  // x^T tile [n 64][c 256] bf16
  __shared__ __align__(16) u16 Bsh[64 * 264];  // W tile; also fp32-transpose scratch
  int t = threadIdx.x, w = t >> 6, lane = t & 63, lr = lane & 15, q = lane >> 4;
  int n0 = blockIdx.x * 64, h2 = blockIdx.y, b = blockIdx.z;
  const float* xb = x + (long)b * C * NN;

  // stage Ash[n][c] = bf16(x[c][n0+n]) via fp32 LDS tiles (in Bsh scratch)
  {
    float* tf = (float*)Bsh;  // 32 x 65 fp32 = 8320 B
#pragma unroll 1
    for (int cblk = 0; cblk < 8; ++cblk) {
      int c0 = cblk * 32;
      int n = t & 63, cg = t >> 6;
#pragma unroll
      for (int r = 0; r < 8; ++r) {
        int c = cg * 8 + r;
        tf[c * 65 + n] = xb[(long)(c0 + c) * NN + n0 + n];  // coalesced along n
      }
      __syncthreads();
      {
        u16 pk[8];
#pragma unroll
        for (int j = 0; j < 8; ++j) pk[j] = f2bf(tf[(cg * 8 + j) * 65 + n]);
        *reinterpret_cast<uint4*>(Ash + n * 264 + c0 + cg * 8) =
            *reinterpret_cast<const uint4*>(pk);
      }
      __syncthreads();
    }
  }

#pragma unroll 1
  for (int ph = 0; ph < 6; ++ph) {
    int wsel = ph >> 1, ot = h2 * 2 + (ph & 1);
    const float* W = wsel == 0 ? wq : wsel == 1 ? wk : wv;
    const float* bias = wsel == 0 ? bq : wsel == 1 ? bk : bv;
    // stage Bsh[o 64][c 256] bf16 from fp32 weights
#pragma unroll
    for (int i = 0; i < 8; ++i) {
      int id = t + i * 256, row = id >> 5, ch = id & 31;
      const float4* wp4 = reinterpret_cast<const float4*>(W + (long)(ot * 64 + row) * C + ch * 8);
      float4 f0 = wp4[0], f1 = wp4[1];
      u16 pk[8] = {f2bf(f0.x), f2bf(f0.y), f2bf(f0.z), f2bf(f0.w),
                   f2bf(f1.x), f2bf(f1.y), f2bf(f1.z), f2bf(f1.w)};
      *reinterpret_cast<uint4*>(Bsh + row * 264 + ch * 8) =
          *reinterpret_cast<const uint4*>(pk);
    }
    __syncthreads();
    v4f acc[4];
#pragma unroll
    for (int nt = 0; nt < 4; ++nt)
#pragma unroll
      for (int r = 0; r < 4; ++r) acc[nt][r] = 0.f;
#pragma unroll
    for (int ks = 0; ks < 8; ++ks) {
      v8bf a = *reinterpret_cast<const v8bf*>(Ash + (w * 16 + lr) * 264 + ks * 32 + q * 8);
#pragma unroll
      for (int nt = 0; nt < 4; ++nt) {
        v8bf bb = *reinterpret_cast<const v8bf*>(Bsh + (nt * 16 + lr) * 264 + ks * 32 + q * 8);
        acc[nt] = __builtin_amdgcn_mfma_f32_16x16x32_bf16(a, bb, acc[nt], 0, 0, 0);
      }
    }
    if (wsel < 2) {
      u16* dst = (wsel == 0 ? qO : kO) + (long)b * NN * C;
      float sc = wsel == 0 ? (0.0625f * LOG2E) : 1.0f;
#pragma unroll
      for (int nt = 0; nt < 4; ++nt) {
#pragma unroll
        for (int r = 0; r < 4; ++r) {
          int gm = n0 + w * 16 + q * 4 + r;        // voxel
          int gn = ot * 64 + nt * 16 + lr;         // out channel
          dst[(long)gm * C + gn] = f2bf((acc[nt][r] + bias[gn]) * sc);
        }
      }
      __syncthreads();  // all Bsh reads done before next phase restages
    } else {
      // V: transpose 64ch x 64vox through Bsh scratch, coalesced store (B,C,N)
      __syncthreads();  // waves done reading Bsh(W) before scatter
      u16* vtr = Bsh;   // [64][72]
#pragma unroll
      for (int nt = 0; nt < 4; ++nt)
#pragma unroll
        for (int r = 0; r < 4; ++r) {
          int lc = nt * 16 + lr;
          int lv = w * 16 + q * 4 + r;
          vtr[lc * 72 + lv] = f2bf(acc[nt][r] + bias[ot * 64 + lc]);
        }
      __syncthreads();
      int row = t >> 2, ch = (t & 3) * 16;
      u16* vdst = vO + ((long)b * C + ot * 64 + row) * NN + n0 + ch;
      *reinterpret_cast<uint4*>(vdst) =
          *reinterpret_cast<const uint4*>(vtr + row * 72 + ch);
      *reinterpret_cast<uint4*>(vdst + 8) =
          *reinterpret_cast<const uint4*>(vtr + row * 72 + ch + 8);
      __syncthreads();
    }
  }
}

// ---------- flash attention: 32x32x16, BM=128, BN=32, static-bound softmax ------
// K,V staged global->VGPR->padded+swizzled LDS, double-buffered; prefetch loads
// issued after the store so staging regs never coexist with the next load set.
__global__ __launch_bounds__(256, 2) void k_flash(
    const u16* __restrict__ qT, const u16* __restrict__ kT, const u16* __restrict__ V,
    u16* __restrict__ op0, u16* __restrict__ op1, u16* __restrict__ op2,
    u16* __restrict__ op3, float* __restrict__ lsum, int span, int lp2) {
  __shared__ __align__(16) u16 ksh[2 * 32 * KP];   // 33 KB
  __shared__ __align__(16) u16 vsh[2 * 256 * VP];  // 36 KB
  __shared__ __align__(16) u16 psh[4 * 32 * PP];   // 9 KB per-wave P
  int t = threadIdx.x;
  int w = t >> 6, lane = t & 63, h5 = lane >> 5, l31 = lane & 31;
  int id = blockIdx.x;
  int p = id & ((1 << lp2) - 1);  // XCD-locality: pair p pinned to one XCD
  int xb = id >> lp2;
  int h = p >> 2, b = p & 3;      // CB == 4
  int i0 = xb * 128;
  const u16* kb = kT + (long)b * NN * C;
  const u16* vb = V + (long)b * C * NN;

  // Q fragments (A-operand), 64 VGPRs
  const u16* qrow = qT + ((long)b * NN + i0 + w * 32 + l31) * C + h5 * 8;
  v8bf qf[16];
#pragma unroll
  for (int ck = 0; ck < 16; ++ck)
    qf[ck] = *reinterpret_cast<const v8bf*>(qrow + ck * 16);

  v16f accO[8];
#pragma unroll
  for (int ct = 0; ct < 8; ++ct)
#pragma unroll
    for (int r = 0; r < 16; ++r) accO[ct][r] = 0.f;
  float lsacc = 0.f;

  u16* pw = psh + w * (32 * PP);
  // staging roles: K: 4 passes of (row s*8 + t>>5, chunk t&31) -> coalesced 512B
  int krow = t >> 5, kchunk = t & 31;
  int vc = t >> 2, vq = t & 3;
  uint4 kreg[4], vreg[4];

  int jstart = h * span;
  int niter = span >> 5;

#define LOAD_TILE(j0)                                                               \
  {                                                                                 \
    _Pragma("unroll") for (int s = 0; s < 4; ++s) {                                 \
      int row = s * 8 + krow;                                                       \
      kreg[s] = *reinterpret_cast<const uint4*>(kb + (long)((j0) + row) * C +       \
                                                kchunk * 8);                        \
    }                                                                               \
    _Pragma("unroll") for (int s = 0; s < 4; ++s) vreg[s] =                         \
        *reinterpret_cast<const uint4*>(vb + (long)(s * 64 + vc) * NN + (j0) +      \
                                        vq * 8);                                    \
  }
#define STORE_TILE(buf)                                                             \
  {                                                                                 \
    u16* kd = ksh + (buf) * (32 * KP);                                              \
    u16* vd = vsh + (buf) * (256 * VP);                                             \
    _Pragma("unroll") for (int s = 0; s < 4; ++s) {                                 \
      int row = s * 8 + krow;                                                       \
      int pos = kchunk ^ (((row >> 3) & 3) << 1);                                   \
      *reinterpret_cast<uint4*>(kd + row * KP + pos * 8) = kreg[s];                 \
    }                                                                               \
    _Pragma("unroll") for (int s = 0; s < 4; ++s)                                   \
        *reinterpret_cast<uint4*>(vd + (s * 64 + vc) * VP + vq * 8) = vreg[s];      \
  }

  // preload tile 0 (+ issue tile 1 loads)
  LOAD_TILE(jstart);
  STORE_TILE(0);
  if (niter > 1) LOAD_TILE(jstart + 32);
  __syncthreads();

  const int xkey = ((l31 >> 3) & 3) << 1;  // must match STORE_TILE's K swizzle
  int cur = 0;
#pragma unroll 1
  for (int it = 0; it < niter; ++it) {
    const u16* kcur = ksh + cur * (32 * KP);
    const u16* vcur = vsh + cur * (256 * VP);

    // S(32x32) = Q . K^T
    v16f s;
#pragma unroll
    for (int r = 0; r < 16; ++r) s[r] = 0.f;
#pragma unroll
    for (int ck = 0; ck < 16; ++ck) {
      int pos = ((ck * 2 + h5) ^ xkey) * 8;
      v8bf kf = *reinterpret_cast<const v8bf*>(kcur + l31 * KP + pos);
      s = __builtin_amdgcn_mfma_f32_32x32x16_bf16(qf[ck], kf, s, 0, 0, 0);
    }
    // p = 2^(s - M) -> per-wave LDS (A-layout target)
#pragma unroll
    for (int r = 0; r < 16; ++r) {
      float pv = exp2f(s[r] - MBOUND);
      u32 pb = (__float_as_uint(pv) + 0x8000u) >> 16;
      int irow = (r & 3) + 8 * (r >> 2) + 4 * h5;
      pw[irow * PP + l31] = (u16)pb;
    }
    asm volatile("s_waitcnt lgkmcnt(0)" ::: "memory");  // same-wave P RAW

    // O += P . V^T ; l recovered from pa fragments (rounded-P-consistent)
#pragma unroll
    for (int kh = 0; kh < 2; ++kh) {
      v8bf pa = *reinterpret_cast<const v8bf*>(pw + l31 * PP + kh * 16 + h5 * 8);
#pragma unroll
      for (int j = 0; j < 8; ++j) lsacc += (float)pa[j];
#pragma unroll
      for (int ct = 0; ct < 8; ++ct) {
        v8bf vf = *reinterpret_cast<const v8bf*>(
            vcur + (ct * 32 + l31) * VP + (kh * 2 + h5) * 8);
        accO[ct] = __builtin_amdgcn_mfma_f32_32x32x16_bf16(pa, vf, accO[ct], 0, 0, 0);
      }
    }

    if (it + 1 < niter) {
      // all waves past their reads of buffer [cur^1] (they read [cur] this iter);
      // vmcnt(0): staged regs have landed
      asm volatile("s_waitcnt vmcnt(0) lgkmcnt(0)\ns_barrier" ::: "memory");
      STORE_TILE(cur ^ 1);
      if (it + 2 < niter) LOAD_TILE(jstart + ((it + 2) << 5));
      // writes visible; next loads stay in flight
      asm volatile("s_waitcnt lgkmcnt(0)\ns_barrier" ::: "memory");
    }
    cur ^= 1;
  }
#undef LOAD_TILE
#undef STORE_TILE

  // per-row l: halves merge across h5, lane l31 then holds row l31's full sum
  lsacc += __shfl_xor(lsacc, 32, 64);
  u16* opp = h == 0 ? op0 : h == 1 ? op1 : h == 2 ? op2 : op3;
  u16* ob = opp + ((long)b * NN + i0 + w * 32) * C;
#pragma unroll
  for (int r = 0; r < 16; ++r) {
    int irow = (r & 3) + 8 * (r >> 2) + 4 * h5;
    float lrow = __shfl(lsacc, irow, 64);
    float inv = 1.0f / lrow;
#pragma unroll
    for (int ct = 0; ct < 8; ++ct)
      ob[(long)irow * C + ct * 32 + l31] = f2bf(accO[ct][r] * inv);
  }
  if (h5 == 0) {
    float* lb = lsum + ((long)h * CB + b) * NN + i0 + w * 32;
    lb[l31] = lsacc;
  }
}

// ---------- fused combine + output projection + residual ----------
// Grid (64, 2, CB): blend once per block, 2 ot phases. wp fp32 direct.
__global__ __launch_bounds__(256) void k_out(
    const u16* __restrict__ p0, const u16* __restrict__ p1, const u16* __restrict__ p2,
    const u16* __restrict__ p3, const float* __restrict__ lsum,
    const float* __restrict__ wp, const float* __restrict__ bp,
    const float* __restrict__ x, float* __restrict__ out, int js) {
  __shared__ __align__(16) u16 Ash[64 * 264];  // blended attn tile [vox][c]
  __shared__ __align__(16) u16 Bsh[64 * 264];  // wp tile per phase
  int t = threadIdx.x, w = t >> 6, lane = t & 63, lr = lane & 15, q = lane >> 4;
  int n0 = blockIdx.x * 64, h2 = blockIdx.y, b = blockIdx.z;
  const u16* ps[4] = {p0, p1, p2, p3};

  // blend partials into Ash (weights = l_h; all partials share static M)
#pragma unroll
  for (int i = 0; i < 8; ++i) {
    int id = t + i * 256, row = id >> 5, ch = id & 31;
    long nrow = (long)b * NN + n0 + row;
    float wsum = 0.f, wgt[4];
    for (int hh = 0; hh < js; ++hh) {
      wgt[hh] = lsum[(long)hh * CB * NN + nrow];
      wsum += wgt[hh];
    }
    float inv = 1.0f / wsum;
    float accv[8];
#pragma unroll
    for (int j = 0; j < 8; ++j) accv[j] = 0.f;
    for (int hh = 0; hh < js; ++hh) {
      uint4 u = *reinterpret_cast<const uint4*>(ps[hh] + nrow * C + ch * 8);
      const u16* pe = reinterpret_cast<const u16*>(&u);
      float g = wgt[hh] * inv;
#pragma unroll
      for (int j = 0; j < 8; ++j) accv[j] += g * bf2f(pe[j]);
    }
    u16 pk[8];
#pragma unroll
    for (int j = 0; j < 8; ++j) pk[j] = f2bf(accv[j]);
    *reinterpret_cast<uint4*>(Ash + row * 264 + ch * 8) =
        *reinterpret_cast<const uint4*>(pk);
  }

#pragma unroll 1
  for (int ph = 0; ph < 2; ++ph) {
    int ot = h2 * 2 + ph;
    __syncthreads();  // prior phase reads done / blend visible
    // stage wp tile from fp32
#pragma unroll
    for (int i = 0; i < 8; ++i) {
      int id = t + i * 256, row = id >> 5, ch = id & 31;
      const float4* wp4 = reinterpret_cast<const float4*>(wp + (long)(ot * 64 + row) * C + ch * 8);
      float4 f0 = wp4[0], f1 = wp4[1];
      u16 pk[8] = {f2bf(f0.x), f2bf(f0.y), f2bf(f0.z), f2bf(f0.w),
                   f2bf(f1.x), f2bf(f1.y), f2bf(f1.z), f2bf(f1.w)};
      *reinterpret_cast<uint4*>(Bsh + row * 264 + ch * 8) =
          *reinterpret_cast<const uint4*>(pk);
    }
    __syncthreads();
    v4f acc[4];
#pragma unroll
    for (int nt = 0; nt < 4; ++nt)
#pragma unroll
      for (int r = 0; r < 4; ++r) acc[nt][r] = 0.f;
#pragma unroll
    for (int ks = 0; ks < 8; ++ks) {
      v8bf a = *reinterpret_cast<const v8bf*>(Bsh + (w * 16 + lr) * 264 + ks * 32 + q * 8);
#pragma unroll
      for (int nt = 0; nt < 4; ++nt) {
        v8bf bb = *reinterpret_cast<const v8bf*>(Ash + (nt * 16 + lr) * 264 + ks * 32 + q * 8);
        acc[nt] = __builtin_amdgcn_mfma_f32_16x16x32_bf16(a, bb, acc[nt], 0, 0, 0);
      }
    }
#pragma unroll
    for (int nt = 0; nt < 4; ++nt) {
#pragma unroll
      for (int r = 0; r < 4; ++r) {
        int gm = ot * 64 + w * 16 + q * 4 + r;   // out channel
        int gn = n0 + nt * 16 + lr;              // voxel
        long addr = ((long)b * C + gm) * NN + gn;
        out[addr] = acc[nt][r] + bp[gm] + x[addr];
      }
    }
  }
}

extern "C" void kernel_launch(void* const* d_in, const int* in_sizes, int n_in,
                              void* d_out, int out_size, void* d_ws, size_t ws_size,
                              hipStream_t stream) {
  const float* x = (const float*)d_in[0];
  const float* wq = (const float*)d_in[1];
  const float* bq = (const float*)d_in[2];
  const float* wk = (const float*)d_in[3];
  const float* bk = (const float*)d_in[4];
  const float* wv = (const float*)d_in[5];
  const float* bv = (const float*)d_in[6];
  const float* wp = (const float*)d_in[7];
  const float* bp = (const float*)d_in[8];
  float* out = (float*)d_out;
  char* ws = (char*)d_ws;

  const long SLOT = 8388608L;
  const size_t NEED4 = 7 * 8388608UL + 262144UL;
  int js = (ws_size >= NEED4) ? 4 : 2;
  int pairs = js * CB;
  int lp2 = (js == 4) ? 4 : 3;

  u16* qTw = (u16*)(ws + 0 * SLOT);
  u16* kTw = (u16*)(ws + 1 * SLOT);
  u16* vw  = (u16*)(ws + 2 * SLOT);
  u16* op0 = (u16*)(ws + 3 * SLOT);
  u16* op1 = (u16*)(ws + 4 * SLOT);
  u16* op2 = js == 4 ? (u16*)(ws + 5 * SLOT) : op1;
  u16* op3 = js == 4 ? (u16*)(ws + 6 * SLOT) : op1;
  float* lsum = (float*)(ws + (js == 4 ? 7 : 5) * SLOT);  // js*CB*NN floats

  k_qkv<<<dim3(64, 2, CB), 256, 0, stream>>>(x, wq, wk, wv, bq, bk, bv, qTw, kTw, vw);
  k_flash<<<32 * pairs, 256, 0, stream>>>(qTw, kTw, vw, op0, op1, op2, op3,
                                          lsum, NN / js, lp2);
  k_out<<<dim3(64, 2, CB), 256, 0, stream>>>(op0, op1, op2, op3, lsum, wp, bp,
                                             x, out, js);
}